// Round 2
// 119.628 us; speedup vs baseline: 1.0072x; 1.0072x over previous
//
#include <hip/hip_runtime.h>

#define N_ELEM    1000000
#define N_NODES   500000
#define NT_P1     250000            // one thread per 4 consecutive elements
#define NT_EXT    125000            // one thread per 12 floats (3 float4) of external work
#define NBLOCKS_M 977               // ceil(250000/256)

typedef float vf4  __attribute__((ext_vector_type(4)));
typedef float vf4a __attribute__((ext_vector_type(4), aligned(4)));  // dword-aligned 16B load
typedef float vf3a __attribute__((ext_vector_type(3), aligned(4)));  // dword-aligned 12B load
typedef int   vi4  __attribute__((ext_vector_type(4)));

__device__ __forceinline__ vf4 nt_v4(const vf4* p) { return __builtin_nontemporal_load(p); }
__device__ __forceinline__ vi4 nt_i4(const vi4* p) { return __builtin_nontemporal_load(p); }

__device__ __forceinline__ float block_reduce(float v) {
    #pragma unroll
    for (int off = 32; off > 0; off >>= 1)
        v += __shfl_down(v, off, 64);
    __shared__ float wave_part[4];
    const int lane = threadIdx.x & 63;
    const int wave = threadIdx.x >> 6;
    if (lane == 0) wave_part[wave] = v;
    __syncthreads();
    return wave_part[0] + wave_part[1] + wave_part[2] + wave_part[3];
}

// Exact 12B gather (global_load_dwordx3): always in-bounds (3n+3 <= 1.5M),
// no last-node special case, fewer 64B-line crossings than a 16B load.
__device__ __forceinline__ void load_node(const float* __restrict__ pred, int n,
                                          float& x, float& y, float& z) {
    const vf3a v = *(const vf3a*)(pred + 3 * n);
    x = v.x; y = v.y; z = v.z;
}

__device__ __forceinline__ float elem_energy(float c, float s, float L,
                                             float E, float A, float I,
                                             float a0, float a1, float tA_r,
                                             float b0, float b1, float tB_r,
                                             float u_c, float theta_c) {
    const float invL = 1.0f / L;
    const float ea_L  = E * A * invL;
    const float ei_L  = E * I * invL;
    const float ei_L2 = ei_L * invL;
    const float ei_L3 = ei_L2 * invL;
    const float d0 = (a0 - b0) * u_c, d1 = (a1 - b1) * u_c;
    const float du =  c * d0 + s * d1;
    const float dw = -s * d0 + c * d1;
    const float tA = tA_r * theta_c, tB = tB_r * theta_c;
    return 0.5f * (ea_L * du * du
                 + 12.0f * ei_L3 * dw * dw
                 + 12.0f * ei_L2 * dw * (tA + tB)
                 + 4.0f  * ei_L  * (tA * tA + tB * tB + tA * tB));
}

// ---- pass 1: strain energy (4 consecutive elements/thread) + external work ----
__global__ __launch_bounds__(256) void frame_energy_kernel(
    const float* __restrict__ pred_raw,
    const float* __restrict__ elem_L,
    const float* __restrict__ prop_E,
    const float* __restrict__ prop_A,
    const float* __restrict__ prop_I,
    const float* __restrict__ dirs,
    const float* __restrict__ F_ext,
    const float* __restrict__ u_c_p,
    const float* __restrict__ theta_c_p,
    const int*   __restrict__ conn,
    float* __restrict__ partials)
{
    const float u_c     = u_c_p[0];
    const float theta_c = theta_c_p[0];

    const int t = blockIdx.x * 256 + threadIdx.x;
    float acc = 0.0f;

    if (t < NT_P1) {
        // elements e = 4t .. 4t+3; all payload loads 16B wide & coalesced
        const vi4 cc0 = nt_i4((const vi4*)conn + 2 * t);        // nA0,nB0,nA1,nB1
        const vi4 cc1 = nt_i4((const vi4*)conn + 2 * t + 1);    // nA2,nB2,nA3,nB3

        // issue all 8 gathers first (MLP)
        float a0x,a0y,a0z, b0x,b0y,b0z;
        float a1x,a1y,a1z, b1x,b1y,b1z;
        float a2x,a2y,a2z, b2x,b2y,b2z;
        float a3x,a3y,a3z, b3x,b3y,b3z;
        load_node(pred_raw, cc0.x, a0x,a0y,a0z);
        load_node(pred_raw, cc0.y, b0x,b0y,b0z);
        load_node(pred_raw, cc0.z, a1x,a1y,a1z);
        load_node(pred_raw, cc0.w, b1x,b1y,b1z);
        load_node(pred_raw, cc1.x, a2x,a2y,a2z);
        load_node(pred_raw, cc1.y, b2x,b2y,b2z);
        load_node(pred_raw, cc1.z, a3x,a3y,a3z);
        load_node(pred_raw, cc1.w, b3x,b3y,b3z);

        const vf4 Lv = nt_v4((const vf4*)elem_L + t);
        const vf4 Ev = nt_v4((const vf4*)prop_E + t);
        const vf4 Av = nt_v4((const vf4*)prop_A + t);
        const vf4 Iv = nt_v4((const vf4*)prop_I + t);

        // dirs floats [12t, 12t+12): layout (c,0,s) per element
        const vf4 d0 = nt_v4((const vf4*)dirs + 3 * t);       // c0 0 s0 c1
        const vf4 d1 = nt_v4((const vf4*)dirs + 3 * t + 1);   // 0 s1 c2 0
        const vf4 d2 = nt_v4((const vf4*)dirs + 3 * t + 2);   // s2 c3 0 s3

        acc += elem_energy(d0.x, d0.z, Lv.x, Ev.x, Av.x, Iv.x,
                           a0x,a0y,a0z, b0x,b0y,b0z, u_c, theta_c);
        acc += elem_energy(d0.w, d1.y, Lv.y, Ev.y, Av.y, Iv.y,
                           a1x,a1y,a1z, b1x,b1y,b1z, u_c, theta_c);
        acc += elem_energy(d1.z, d2.x, Lv.z, Ev.z, Av.z, Iv.z,
                           a2x,a2y,a2z, b2x,b2y,b2z, u_c, theta_c);
        acc += elem_energy(d2.y, d2.w, Lv.w, Ev.w, Av.w, Iv.w,
                           a3x,a3y,a3z, b3x,b3y,b3z, u_c, theta_c);
    }

    // ---- external work: threads 0..124999 handle floats [12t, 12t+12).
    // (12t+k) % 3 == k % 3  ==>  scale pattern is compile-time constant.
    if (t < NT_EXT) {
        const vf4a* pp = (const vf4a*)pred_raw + 3 * t;
        const vf4*  fp = (const vf4*)F_ext   + 3 * t;
        const vf4 p0 = pp[0], p1 = pp[1], p2 = pp[2];
        const vf4 f0 = nt_v4(fp), f1 = nt_v4(fp + 1), f2 = nt_v4(fp + 2);
        // component scales: v0=(u,u,t,u) v1=(u,t,u,u) v2=(t,u,u,t)
        const float su = p0.x*f0.x + p0.y*f0.y + p0.w*f0.w
                       + p1.x*f1.x + p1.z*f1.z + p1.w*f1.w
                       + p2.y*f2.y + p2.z*f2.z;
        const float st = p0.z*f0.z + p1.y*f1.y + p2.x*f2.x + p2.w*f2.w;
        acc -= u_c * su + theta_c * st;
    }

    const float blk = block_reduce(acc);
    if (threadIdx.x == 0) partials[blockIdx.x] = blk;   // distinct lines, no atomics
}

// ---- pass 2: single-block finisher ----
__global__ __launch_bounds__(256) void finish_kernel(
    const float* __restrict__ partials,
    const float* __restrict__ u_c_p,
    const float* __restrict__ F_c_p,
    float* __restrict__ out)
{
    float v = 0.0f;
    for (int i = threadIdx.x; i < NBLOCKS_M; i += 256)
        v += partials[i];
    const float total = block_reduce(v);
    if (threadIdx.x == 0) {
        const float inv_Ec = 1.0f / fmaxf(F_c_p[0] * u_c_p[0], 1e-30f);
        out[0] = total * inv_Ec;
    }
}

extern "C" void kernel_launch(void* const* d_in, const int* in_sizes, int n_in,
                              void* d_out, int out_size, void* d_ws, size_t ws_size,
                              hipStream_t stream) {
    const float* pred_raw = (const float*)d_in[0];
    const float* elem_L   = (const float*)d_in[1];
    const float* prop_E   = (const float*)d_in[2];
    const float* prop_A   = (const float*)d_in[3];
    const float* prop_I   = (const float*)d_in[4];
    const float* dirs     = (const float*)d_in[5];
    const float* F_ext    = (const float*)d_in[6];
    const float* u_c      = (const float*)d_in[7];
    const float* theta_c  = (const float*)d_in[8];
    const float* F_c      = (const float*)d_in[9];
    const int*   conn     = (const int*)d_in[10];
    float* out = (float*)d_out;
    float* partials = (float*)d_ws;   // 977 floats

    frame_energy_kernel<<<NBLOCKS_M, 256, 0, stream>>>(
        pred_raw, elem_L, prop_E, prop_A, prop_I, dirs, F_ext,
        u_c, theta_c, conn, partials);
    finish_kernel<<<1, 256, 0, stream>>>(partials, u_c, F_c, out);
}